// Round 3
// 5471.187 us; speedup vs baseline: 4.8850x; 4.8850x over previous
//
#include <hip/hip_runtime.h>
#include <hip/hip_bf16.h>
#include <math.h>

#define T_STEPS 512
#define B_SZ 256
#define I_SZ 256
#define H_SZ 1024

typedef unsigned short u16;
typedef __bf16 bf16x8 __attribute__((ext_vector_type(8)));
typedef float f32x4 __attribute__((ext_vector_type(4)));

__device__ __forceinline__ u16 f2bf(float f) {
    union { float f; unsigned u; } v; v.f = f;
    unsigned r = v.u + 0x7fffu + ((v.u >> 16) & 1u);  // RNE
    return (u16)(r >> 16);
}

// L3-coherent (agent coherence point) 16B load: bypasses L1+L2 via sc0 sc1.
// Consumers never need a cache-invalidate fence; data is read at MALL.
template<int OFF>
__device__ __forceinline__ bf16x8 ld_b128_sc(const u16* p) {
    bf16x8 r;
    asm volatile("global_load_dwordx4 %0, %1, off offset:%2 sc0 sc1"
                 : "=v"(r) : "v"(p), "i"(OFF));
    return r;
}

// L3-coherent 2B store: write-through to MALL, bypass L1+L2.
// vmcnt retire == committed at the coherence point, so the release pattern is
// just s_waitcnt vmcnt(0) — no buffer_wbl2 (the per-step full-L2 flush that
// dominated the previous kernel).
__device__ __forceinline__ void st_b16_sc(u16* p, unsigned v) {
    asm volatile("global_store_short %0, %1, off sc0 sc1"
                 :: "v"(p), "v"(v) : "memory");
}

__device__ __forceinline__ f32x4 mm(bf16x8 a, bf16x8 b, f32x4 c) {
    return __builtin_amdgcn_mfma_f32_16x16x32_bf16(a, b, c, 0, 0, 0);
}

// counted waitcnt + scheduling fence (rule #18: MFMAs otherwise hoist past
// an inline-asm waitcnt because they are register-only ops)
#define WAITV(N) do { \
    asm volatile("s_waitcnt vmcnt(" #N ")" ::: "memory"); \
    __builtin_amdgcn_sched_barrier(0); \
} while (0)

#define LD_GRP(arr, B0) do { \
    arr[0] = ld_b128_sc<((B0)+0)*64>(hrow); \
    arr[1] = ld_b128_sc<((B0)+1)*64>(hrow); \
    arr[2] = ld_b128_sc<((B0)+2)*64>(hrow); \
    arr[3] = ld_b128_sc<((B0)+3)*64>(hrow); \
    arr[4] = ld_b128_sc<((B0)+4)*64>(hrow); \
    arr[5] = ld_b128_sc<((B0)+5)*64>(hrow); \
    arr[6] = ld_b128_sc<((B0)+6)*64>(hrow); \
    arr[7] = ld_b128_sc<((B0)+7)*64>(hrow); \
} while (0)

#define MM_GRP(arr, B0) do { \
    acc0 = mm(arr[0], wB[(B0)+0], acc0); \
    acc1 = mm(arr[1], wB[(B0)+1], acc1); \
    acc2 = mm(arr[2], wB[(B0)+2], acc2); \
    acc3 = mm(arr[3], wB[(B0)+3], acc3); \
    acc0 = mm(arr[4], wB[(B0)+4], acc0); \
    acc1 = mm(arr[5], wB[(B0)+5], acc1); \
    acc2 = mm(arr[6], wB[(B0)+6], acc2); \
    acc3 = mm(arr[7], wB[(B0)+7], acc3); \
} while (0)

// ---------------------------------------------------------------------------
// prep: fp32 -> bf16 conversions of weights + h0, zero team barrier counters.
// ws layout: [0,2MB) W_hh bf16 | [2MB,2.5MB) W_ih bf16 | hp0 512KB | hp1 512KB | ctr
// ---------------------------------------------------------------------------
__global__ void prep_kernel(const float* __restrict__ wih, const float* __restrict__ whh,
                            const float* __restrict__ h0,
                            u16* __restrict__ whh_b, u16* __restrict__ wih_b,
                            u16* __restrict__ hp0, unsigned* __restrict__ ctr) {
    int idx = blockIdx.x * blockDim.x + threadIdx.x;
    int stride = gridDim.x * blockDim.x;
    for (int i = idx; i < H_SZ * H_SZ; i += stride) whh_b[i] = f2bf(whh[i]);
    for (int i = idx; i < H_SZ * I_SZ; i += stride) wih_b[i] = f2bf(wih[i]);
    for (int i = idx; i < B_SZ * H_SZ; i += stride) hp0[i] = f2bf(h0[i]);
    if (idx < 8) ctr[idx] = 0;
}

// ---------------------------------------------------------------------------
// Persistent RNN kernel.
// Grid: 256 blocks x 256 threads (4 waves). 8 teams of 32 blocks:
//   team = blockIdx%8 -> batch rows [32*team, 32*team+32)
//   slice = blockIdx/8 -> hidden cols [32*slice, 32*slice+32)
// W_hh/W_ih slices pinned in registers (AGPR side of the unified file).
// Cross-block h handoff rides entirely at the L3 coherence point:
//   publish  : global_store_short sc0 sc1 (bypass L1/L2)
//   release  : s_waitcnt vmcnt(0) + __syncthreads + RELAXED agent fetch_add
//   consume  : global_load_dwordx4 sc0 sc1, 4x8 pipelined, counted vmcnt(8)
// No __threadfence anywhere in the loop => no buffer_wbl2 / buffer_inv
// full-L2 walks per step (the previous 52 us/step bottleneck).
// ---------------------------------------------------------------------------
__global__ void __launch_bounds__(256, 1)
rnn_persistent(const float* __restrict__ x, const float* __restrict__ h0,
               const float* __restrict__ bias,
               const u16* __restrict__ whh_b, const u16* __restrict__ wih_b,
               u16* __restrict__ hp0, u16* __restrict__ hp1,
               unsigned* __restrict__ ctr, float* __restrict__ out)
{
    const int tid  = threadIdx.x;
    const int wid  = tid >> 6;
    const int lane = tid & 63;
    const int l16  = lane & 15;
    const int quad = lane >> 4;

    const int team  = blockIdx.x & 7;
    const int slice = blockIdx.x >> 3;

    const int row_base = team * 32 + (wid & 1) * 16;         // wave's 16 batch rows
    const int gcol     = slice * 32 + (wid >> 1) * 16 + l16; // lane's hidden col
    const int am       = row_base + l16;                     // lane's A-frag row
    const int kq       = quad * 8;                           // lane's k base

    // Pin W_hh / W_ih B-fragments in registers (persistent across all 512 steps)
    bf16x8 wB[32];
#pragma unroll
    for (int kk = 0; kk < 32; ++kk)
        wB[kk] = *reinterpret_cast<const bf16x8*>(whh_b + gcol * H_SZ + kk * 32 + kq);
    bf16x8 wI[8];
#pragma unroll
    for (int kx = 0; kx < 8; ++kx)
        wI[kx] = *reinterpret_cast<const bf16x8*>(wih_b + gcol * I_SZ + kx * 32 + kq);

    const float bias_v = bias[gcol];

    // fp32 master copy of this lane's 4 h elements (C-layout: row=quad*4+i, col=l16)
    float hown[4];
#pragma unroll
    for (int i = 0; i < 4; ++i)
        hown[i] = h0[(row_base + quad * 4 + i) * H_SZ + gcol];

    unsigned* my_ctr = ctr + team;

    for (int t = 0; t < T_STEPS; ++t) {
        const u16* hcur = (t & 1) ? hp1 : hp0;
        u16*       hnxt = (t & 1) ? hp0 : hp1;

        f32x4 acc0 = {0.f,0.f,0.f,0.f}, acc1 = {0.f,0.f,0.f,0.f};
        f32x4 acc2 = {0.f,0.f,0.f,0.f}, acc3 = {0.f,0.f,0.f,0.f};

        // ---- x_t @ W_ih^T : independent of the barrier, issue first ----
        const float* xrow = x + (size_t)t * (B_SZ * I_SZ) + am * I_SZ + kq;
#pragma unroll
        for (int kx = 0; kx < 8; ++kx) {
            f32x4 x0 = *reinterpret_cast<const f32x4*>(xrow + kx * 32);
            f32x4 x1 = *reinterpret_cast<const f32x4*>(xrow + kx * 32 + 4);
            union { u16 u[8]; bf16x8 v; } ax;
#pragma unroll
            for (int j = 0; j < 4; ++j) { ax.u[j] = f2bf(x0[j]); ax.u[4 + j] = f2bf(x1[j]); }
            if ((kx & 3) == 0)      acc0 = mm(ax.v, wI[kx], acc0);
            else if ((kx & 3) == 1) acc1 = mm(ax.v, wI[kx], acc1);
            else if ((kx & 3) == 2) acc2 = mm(ax.v, wI[kx], acc2);
            else                    acc3 = mm(ax.v, wI[kx], acc3);
        }

        // ---- wait until the whole team published h_t (no acquire fence:
        //      h loads below bypass L1/L2, so nothing stale can be read) ----
        if (t > 0) {
            if (tid == 0) {
                const unsigned tgt = 32u * (unsigned)t;
                while (__hip_atomic_load(my_ctr, __ATOMIC_RELAXED, __HIP_MEMORY_SCOPE_AGENT) < tgt)
                    __builtin_amdgcn_s_sleep(1);
            }
            __syncthreads();   // pre-barrier drain also guarantees vmcnt==0 here
        }

        // ---- h_t @ W_hh^T : 4 groups of 8 L3-coherent b128 loads, pipelined
        //      with counted vmcnt so 2 groups stay in flight ----
        const u16* hrow = hcur + am * H_SZ + kq;
        bf16x8 g0[8], g1[8], g2[8], g3[8];
        LD_GRP(g0, 0);
        LD_GRP(g1, 8);
        WAITV(8);          // g0 landed (g1 outstanding)
        MM_GRP(g0, 0);
        LD_GRP(g2, 16);
        WAITV(8);          // g1 landed (g2 outstanding)
        MM_GRP(g1, 8);
        LD_GRP(g3, 24);
        WAITV(8);          // g2 landed (g3 outstanding)
        MM_GRP(g2, 16);
        WAITV(0);          // g3 landed
        MM_GRP(g3, 24);

        // ---- epilogue: bias, tanh, EMA (fp32 master state) ----
        float hn[4];
#pragma unroll
        for (int i = 0; i < 4; ++i) {
            float pre = (acc0[i] + acc1[i]) + (acc2[i] + acc3[i]) + bias_v;
            hn[i] = 0.9f * hown[i] + 0.1f * tanhf(pre);
            hown[i] = hn[i];
        }

        // ---- publish bf16 h_{t+1} straight to L3 (bypass L1/L2) ----
#pragma unroll
        for (int i = 0; i < 4; ++i)
            st_b16_sc(hnxt + (row_base + quad * 4 + i) * H_SZ + gcol,
                      (unsigned)f2bf(hn[i]));

        // release: stores committed at the coherence point once vmcnt==0;
        // RELAXED signal (RELEASE would emit the full-L2 wbl2 again)
        asm volatile("s_waitcnt vmcnt(0)" ::: "memory");
        __syncthreads();
        if (tid == 0)
            __hip_atomic_fetch_add(my_ctr, 1u, __ATOMIC_RELAXED, __HIP_MEMORY_SCOPE_AGENT);

        // ---- fp32 outputs (after signal: off the critical path) ----
        float* orow = out + (size_t)t * (B_SZ * H_SZ);
#pragma unroll
        for (int i = 0; i < 4; ++i)
            orow[(row_base + quad * 4 + i) * H_SZ + gcol] = hn[i];

        if (t == T_STEPS - 1) {
            float* hl = out + (size_t)T_STEPS * (B_SZ * H_SZ);
#pragma unroll
            for (int i = 0; i < 4; ++i)
                hl[(row_base + quad * 4 + i) * H_SZ + gcol] = hn[i];
        }
    }
}

extern "C" void kernel_launch(void* const* d_in, const int* in_sizes, int n_in,
                              void* d_out, int out_size, void* d_ws, size_t ws_size,
                              hipStream_t stream) {
    const float* x    = (const float*)d_in[0];  // [T,B,I]
    const float* h0   = (const float*)d_in[1];  // [1,B,H]
    const float* wih  = (const float*)d_in[2];  // [H,I]
    const float* whh  = (const float*)d_in[3];  // [H,H]
    const float* bias = (const float*)d_in[4];  // [H]
    float* out = (float*)d_out;                 // [T,B,H] ++ [B,H]

    char* ws = (char*)d_ws;
    u16* whh_b = (u16*)(ws);                                   // 2 MB
    u16* wih_b = (u16*)(ws + (size_t)(2u << 20));              // 512 KB
    u16* hp0   = (u16*)(ws + (size_t)(2u << 20) + (1u << 19)); // 512 KB
    u16* hp1   = (u16*)(ws + (size_t)(2u << 20) + (2u << 19)); // 512 KB
    unsigned* ctr = (unsigned*)(ws + (size_t)(2u << 20) + (3u << 19));

    prep_kernel<<<dim3(1024), dim3(256), 0, stream>>>(wih, whh, h0, whh_b, wih_b, hp0, ctr);
    rnn_persistent<<<dim3(256), dim3(256), 0, stream>>>(x, h0, bias, whh_b, wih_b, hp0, hp1, ctr, out);
}